// Round 12
// baseline (1063.572 us; speedup 1.0000x reference)
//
#include <hip/hip_runtime.h>

#pragma clang fp contract(off)

#define NPT 4096
#define B_ 16
#define S_ 1024
#define K_ 32
#define ROWS (B_*S_*K_)   // 524288
#define PNB 1024          // partial-stats blocks (layer kernels' grid)

typedef float v2f __attribute__((ext_vector_type(2)));
typedef unsigned int u32;
typedef unsigned long long u64;
typedef __attribute__((ext_vector_type(8))) short s16x8;
typedef __attribute__((ext_vector_type(4))) float f32x4;
typedef __attribute__((ext_vector_type(8))) unsigned short us8v;

__device__ __forceinline__ float rlf(float v, int l) {
  return __uint_as_float(__builtin_amdgcn_readlane(__float_as_uint(v), l));
}

__device__ __forceinline__ short rne_bf16(float x) {
  u32 b = __float_as_uint(x);
  b += 0x7FFFu + ((b >> 16) & 1u);
  return (short)(b >> 16);
}
__device__ __forceinline__ u32 rne_bits(float x) {   // rounded bits, result in high 16
  u32 b = __float_as_uint(x);
  return b + 0x7FFFu + ((b >> 16) & 1u);
}

__device__ __forceinline__ f32x4 mfma16(s16x8 a, s16x8 b, f32x4 c) {
  return __builtin_amdgcn_mfma_f32_16x16x32_bf16(a, b, c, 0, 0, 0);
}

// stored-position -> original channel permutation for y2 (layer2 fast stores)
__device__ __forceinline__ int permc(int p) { return ((p & 3) << 4) | (p >> 2); }

// BN+relu+RNE-pack for a bf16 pair held in one dword. Bit-exact vs scalar path.
__device__ __forceinline__ u32 bnrelu_pack(u32 d, v2f sc, v2f sh) {
  v2f a;
  a.x = __uint_as_float(d << 16);
  a.y = __uint_as_float(d & 0xFFFF0000u);
  v2f z = __builtin_elementwise_fma(a, sc, sh);
  z = __builtin_elementwise_max(z, (v2f){0.f, 0.f});
  u32 zx = rne_bits(z.x), zy = rne_bits(z.y);
  return __builtin_amdgcn_perm(zy, zx, 0x07060302);   // {zx.hi16, zy.hi16}
}

template <int CTRL>
__device__ __forceinline__ u64 dpp_u64(u64 x) {
  int lo = (int)(u32)x, hi = (int)(u32)(x >> 32);
  lo = __builtin_amdgcn_update_dpp(lo, lo, CTRL, 0xF, 0xF, false);
  hi = __builtin_amdgcn_update_dpp(hi, hi, CTRL, 0xF, 0xF, false);
  return ((u64)(u32)hi << 32) | (u32)lo;
}
// full-wave f64 max -> lane 63. Keys are positive doubles => f64 order == u64 order.
__device__ __forceinline__ double wave_max_f64(double k) {
  k = fmax(k, __longlong_as_double((long long)dpp_u64<0x111>((u64)__double_as_longlong(k))));
  k = fmax(k, __longlong_as_double((long long)dpp_u64<0x112>((u64)__double_as_longlong(k))));
  k = fmax(k, __longlong_as_double((long long)dpp_u64<0x114>((u64)__double_as_longlong(k))));
  k = fmax(k, __longlong_as_double((long long)dpp_u64<0x118>((u64)__double_as_longlong(k))));
  k = fmax(k, __longlong_as_double((long long)dpp_u64<0x142>((u64)__double_as_longlong(k))));
  k = fmax(k, __longlong_as_double((long long)dpp_u64<0x143>((u64)__double_as_longlong(k))));
  return k;
}

__device__ __forceinline__ double mkkey(float d, u32 lo) {
  return __longlong_as_double((long long)(((u64)__float_as_uint(d) << 32) | lo));
}

// ---------------- FPS: one block per batch, 1024 threads, 4 pts/thread ----------------
// Same algorithm as the proven R5/R8 kernel (f64 packed keys, DPP wave max, lane63
// atomicMax, single barrier) — ONLY the thread count changes (512->1024): 4 waves/SIMD
// hides more of the ~460-cyc serial chain; per-wave key tree shrinks 7->3 max_f64.
// R6 showed fewer waves regress; this probes the opposite direction. Revert if >600us.
__global__ __launch_bounds__(1024) void fps_kernel(const float* __restrict__ xyz,
    float* __restrict__ out0, float* __restrict__ new_xyz) {
  const int b = blockIdx.x, t = threadIdx.x;
  const int lane = t & 63;
  const float* xb = xyz + (size_t)b * 3 * NPT;
  __shared__ float4 spt[NPT];       // 64 KB: (x,y,z,-)
  __shared__ u64 skey[3];           // 3-slot rotating argmax cell
  __shared__ int sfar[S_];          // selected index per iteration
  // coalesced stage into LDS
#pragma unroll
  for (int j = 0; j < 4; j++) {
    int m = t + j * 1024;
    spt[m] = make_float4(xb[m], xb[NPT + m], xb[2 * NPT + m], 0.f);
  }
  if (t < 3) skey[t] = 0ull;
  // lane-local consecutive points n = t*4+i, loaded from global (coalesced float4)
  const float4* xb4 = (const float4*)xb;
  float4 X = xb4[t];
  float4 Y = xb4[NPT / 4 + t];
  float4 Z = xb4[2 * NPT / 4 + t];
  v2f px[2], py[2], pz[2], ds[2];
  px[0] = (v2f){X.x, X.y}; px[1] = (v2f){X.z, X.w};
  py[0] = (v2f){Y.x, Y.y}; py[1] = (v2f){Y.z, Y.w};
  pz[0] = (v2f){Z.x, Z.y}; pz[1] = (v2f){Z.z, Z.w};
  const int base = t * 4;
  u32 lo[4];
#pragma unroll
  for (int i = 0; i < 4; i++) lo[i] = ~(u32)(base + i);
  ds[0] = (v2f){1e10f, 1e10f};
  ds[1] = (v2f){1e10f, 1e10f};
  __syncthreads();
  int far = 0, slot = 0;
  for (int it = 0; it < S_; ++it) {
    if (t == 0) sfar[it] = far;
    float4 c = spt[far];
    v2f cx = (v2f){c.x, c.x}, cy = (v2f){c.y, c.y}, cz = (v2f){c.z, c.z};
#pragma unroll
    for (int j = 0; j < 2; j++) {
      // exact ref op order per element: ((dx*dx + dy*dy) + dz*dz), contraction OFF
      v2f dx = px[j] - cx, dy = py[j] - cy, dz = pz[j] - cz;
      v2f s = dx * dx + dy * dy;
      v2f d = s + dz * dz;
      v2f nd;
      nd.x = fminf(ds[j].x, d.x);
      nd.y = fminf(ds[j].y, d.y);
      ds[j] = nd;
    }
    // f64 sortable keys: max dist, tie -> min index (via ~idx in low word)
    double k = fmax(fmax(mkkey(ds[0].x, lo[0]), mkkey(ds[0].y, lo[1])),
                    fmax(mkkey(ds[1].x, lo[2]), mkkey(ds[1].y, lo[3])));
    k = wave_max_f64(k);
    if (lane == 63) atomicMax(&skey[slot], (u64)__double_as_longlong(k));
    __syncthreads();
    u64 kk = skey[slot];
    if (t == 0) skey[slot == 0 ? 2 : slot - 1] = 0ull;  // reset slot (it+2)%3: safe post-barrier
    far = (int)(~(u32)kk);
    slot = (slot == 2) ? 0 : slot + 1;
  }
  __syncthreads();
  // coalesced writeback of centroids (t covers all 1024 iterations)
  {
    int it = t;
    float4 p = spt[sfar[it]];
    out0[(b * 3 + 0) * S_ + it] = p.x;
    out0[(b * 3 + 1) * S_ + it] = p.y;
    out0[(b * 3 + 2) * S_ + it] = p.z;
    float* nz = new_xyz + ((size_t)b * S_ + it) * 3;
    nz[0] = p.x; nz[1] = p.y; nz[2] = p.z;
  }
}

// ---------------- Ball query: one wave per query ----------------
__global__ __launch_bounds__(256) void ballq_kernel(const float* __restrict__ xyz,
    const float* __restrict__ new_xyz, int* __restrict__ gidx) {
  const int wid = (blockIdx.x * 256 + threadIdx.x) >> 6;   // 16384 queries
  const int lane = threadIdx.x & 63;
  const int b = wid >> 10;
  const float* xb = xyz + (size_t)b * 3 * NPT;
  const float qx = new_xyz[(size_t)wid * 3 + 0];
  const float qy = new_xyz[(size_t)wid * 3 + 1];
  const float qz = new_xyz[(size_t)wid * 3 + 2];
  const float R2 = (float)(0.4 * 0.4);
  int* g = gidx + (size_t)wid * K_;
  int cnt = 0, firstIdx = 0x7fffffff;
  for (int c0 = 0; c0 < NPT && cnt < K_; c0 += 64) {
    int n = c0 + lane;
    float dx = __fadd_rn(qx, -xb[n]);
    float dy = __fadd_rn(qy, -xb[NPT + n]);
    float dz = __fadd_rn(qz, -xb[2 * NPT + n]);
    float sq = __fadd_rn(__fadd_rn(__fmul_rn(dx, dx), __fmul_rn(dy, dy)), __fmul_rn(dz, dz));
    bool inr = !(sq > R2);
    unsigned long long m = __ballot(inr);
    if (inr) {
      int pos = cnt + (int)__popcll(m & ((1ull << lane) - 1ull));
      if (pos < K_) g[pos] = n;
    }
    if (firstIdx == 0x7fffffff && m) firstIdx = c0 + (int)__builtin_ctzll(m);
    cnt += (int)__popcll(m);
  }
  if (lane >= cnt && lane < K_) g[lane] = firstIdx;
}

// ---------------- Layer 1: gather+concat, 6->64, 4 rows/wave-iter, bf16 out + stats --------
__global__ __launch_bounds__(256) void layer1_kernel(
    const float* __restrict__ xyz, const float* __restrict__ pts,
    const float* __restrict__ new_xyz, const int* __restrict__ gidx,
    const float* __restrict__ W1, const float* __restrict__ b1,
    unsigned short* __restrict__ y1, float* __restrict__ partials) {
  __shared__ float sp[4 * 2 * 64];
  const int lane = threadIdx.x & 63, wv = threadIdx.x >> 6;
  const int nw = gridDim.x * 4;
  float w[6];
#pragma unroll
  for (int c = 0; c < 6; c++) w[c] = W1[lane * 6 + c];
  const float bias = b1[lane];
  float s0 = 0.f, s1 = 0.f;
  const int grp = lane >> 3;          // 0..7; groups 0..3 gather for rows A..D
  const int gc = lane & 7;            // channel slot within group (0..5 used)
  for (int r = (blockIdx.x * 4 + wv) * 4; r < ROWS; r += nw * 4) {
    float v = 0.f;
    if (grp < 4 && gc < 6) {
      int rr = r + grp;
      int gi = gidx[rr];
      int bs = rr >> 5, bb = bs >> 10;
      if (gc < 3) v = xyz[((size_t)bb * 3 + gc) * NPT + gi] - new_xyz[(size_t)bs * 3 + gc];
      else        v = pts[((size_t)bb * 3 + (gc - 3)) * NPT + gi];
    }
    float acc[4];
#pragma unroll
    for (int q = 0; q < 4; q++) acc[q] = bias;
#pragma unroll
    for (int c = 0; c < 6; c++) {
#pragma unroll
      for (int q = 0; q < 4; q++) acc[q] = fmaf(rlf(v, q * 8 + c), w[c], acc[q]);
    }
#pragma unroll
    for (int q = 0; q < 4; q++) {
      y1[(size_t)(r + q) * 64 + lane] = (unsigned short)rne_bf16(acc[q]);
      s0 += acc[q]; s1 = fmaf(acc[q], acc[q], s1);
    }
  }
  sp[(wv * 2 + 0) * 64 + lane] = s0;
  sp[(wv * 2 + 1) * 64 + lane] = s1;
  __syncthreads();
  if (threadIdx.x < 128) {
    float p = sp[threadIdx.x] + sp[threadIdx.x + 128] + sp[threadIdx.x + 256] + sp[threadIdx.x + 384];
    partials[(size_t)threadIdx.x * PNB + blockIdx.x] = p;
  }
}

// ---------------- Layer 2 (MFMA): bn1+relu (pk) -> GEMM 64->64, 2 M-tiles/iter; permuted-K ----
__global__ __launch_bounds__(256) void layer2_kernel(
    const unsigned short* __restrict__ y1, const float* __restrict__ W,
    const float* __restrict__ bias, const float* __restrict__ bnin,
    unsigned short* __restrict__ y2, float* __restrict__ partials) {
  constexpr int NT = 4;
  const int lane = threadIdx.x & 63, wv = threadIdx.x >> 6;
  const int quad = lane >> 4, l16 = lane & 15;
  s16x8 bfrag[NT][2];
  float biasr[NT];
#pragma unroll
  for (int t = 0; t < NT; t++) {
    int n = l16 + 16 * t;
    biasr[t] = bias[n];
#pragma unroll
    for (int kc = 0; kc < 2; kc++)
#pragma unroll
      for (int j = 0; j < 8; j++)
        bfrag[t][kc][j] = rne_bf16(W[(size_t)n * 64 + kc * 32 + quad * 8 + j]);
  }
  v2f sc2[2][4], sh2[2][4];
#pragma unroll
  for (int kc = 0; kc < 2; kc++)
#pragma unroll
    for (int p = 0; p < 4; p++) {
      int k0 = kc * 32 + quad * 8 + 2 * p;
      sc2[kc][p] = (v2f){bnin[k0], bnin[k0 + 1]};
      sh2[kc][p] = (v2f){bnin[64 + k0], bnin[64 + k0 + 1]};
    }
  float s0[NT], s1[NT];
#pragma unroll
  for (int t = 0; t < NT; t++) { s0[t] = 0.f; s1[t] = 0.f; }
  const int nwaves = gridDim.x * 4;
  for (int mt = (blockIdx.x * 4 + wv) * 2; mt < ROWS / 16; mt += nwaves * 2) {
    const u32* p0 = (const u32*)(y1 + (size_t)(mt * 16 + l16) * 64 + quad * 8);
    const u32* p1 = (const u32*)(y1 + (size_t)((mt + 1) * 16 + l16) * 64 + quad * 8);
    u32 d[2][8];
#pragma unroll
    for (int q = 0; q < 4; q++) { d[0][q] = p0[q]; d[0][4 + q] = p0[16 + q]; }
#pragma unroll
    for (int q = 0; q < 4; q++) { d[1][q] = p1[q]; d[1][4 + q] = p1[16 + q]; }
    s16x8 a[2][2];
#pragma unroll
    for (int m2 = 0; m2 < 2; m2++) {
      u32* a0u = (u32*)&a[m2][0]; u32* a1u = (u32*)&a[m2][1];
#pragma unroll
      for (int q = 0; q < 4; q++) {
        a0u[q] = bnrelu_pack(d[m2][q], sc2[0][q], sh2[0][q]);
        a1u[q] = bnrelu_pack(d[m2][4 + q], sc2[1][q], sh2[1][q]);
      }
    }
    f32x4 acc[2][NT];
#pragma unroll
    for (int m2 = 0; m2 < 2; m2++)
#pragma unroll
      for (int t = 0; t < NT; t++) {
        acc[m2][t] = (f32x4){biasr[t], biasr[t], biasr[t], biasr[t]};
        acc[m2][t] = mfma16(a[m2][0], bfrag[t][0], acc[m2][t]);
        acc[m2][t] = mfma16(a[m2][1], bfrag[t][1], acc[m2][t]);
      }
#pragma unroll
    for (int m2 = 0; m2 < 2; m2++) {
#pragma unroll
      for (int r = 0; r < 4; r++) {
        u32 b01 = __builtin_amdgcn_perm(rne_bits(acc[m2][1][r]), rne_bits(acc[m2][0][r]), 0x07060302);
        u32 b23 = __builtin_amdgcn_perm(rne_bits(acc[m2][3][r]), rne_bits(acc[m2][2][r]), 0x07060302);
        int m = (mt + m2) * 16 + quad * 4 + r;
        *(uint2*)(y2 + (size_t)m * 64 + 4 * l16) = make_uint2(b01, b23);
      }
#pragma unroll
      for (int t = 0; t < NT; t++)
#pragma unroll
        for (int r = 0; r < 4; r++) {
          float v = acc[m2][t][r];
          s0[t] += v; s1[t] = fmaf(v, v, s1[t]);
        }
    }
  }
#pragma unroll
  for (int t = 0; t < NT; t++) {
    s0[t] += __shfl_xor(s0[t], 16); s0[t] += __shfl_xor(s0[t], 32);
    s1[t] += __shfl_xor(s1[t], 16); s1[t] += __shfl_xor(s1[t], 32);
  }
  __shared__ float sp[4 * 2 * 64];
  if (quad == 0) {
#pragma unroll
    for (int t = 0; t < NT; t++) {
      sp[wv * 128 + l16 + 16 * t] = s0[t];
      sp[wv * 128 + 64 + l16 + 16 * t] = s1[t];
    }
  }
  __syncthreads();
  if (threadIdx.x < 128) {
    int tt = threadIdx.x;
    float p = sp[tt] + sp[128 + tt] + sp[256 + tt] + sp[384 + tt];
    partials[(size_t)tt * PNB + blockIdx.x] = p;
  }
}

// ---------------- fold partials -> bn scale/shift ----------------
__global__ __launch_bounds__(256) void finalize_kernel(const float* __restrict__ partials,
    int cout, const float* __restrict__ g, const float* __restrict__ be,
    float* __restrict__ bn) {
  const int c = blockIdx.x;
  const int t = threadIdx.x;
  const int lane = t & 63, wv = t >> 6;
  float s0 = 0.f, s1 = 0.f;
  for (int bb = t; bb < PNB; bb += 256) {
    s0 += partials[(size_t)c * PNB + bb];
    s1 += partials[(size_t)(cout + c) * PNB + bb];
  }
#pragma unroll
  for (int off = 32; off; off >>= 1) {
    s0 += __shfl_xor(s0, off);
    s1 += __shfl_xor(s1, off);
  }
  __shared__ float r0[4], r1[4];
  if (lane == 0) { r0[wv] = s0; r1[wv] = s1; }
  __syncthreads();
  if (t == 0) {
    double d0 = (double)r0[0] + r0[1] + r0[2] + r0[3];
    double d1 = (double)r1[0] + r1[1] + r1[2] + r1[3];
    double N = (double)ROWS;
    double mean = d0 / N;
    double var = d1 / N - mean * mean;
    double scale = (double)g[c] / sqrt(var + 1e-5);
    bn[c] = (float)scale;
    bn[cout + c] = (float)((double)be[c] - mean * scale);
  }
}

// ---------------- Fused layer3: GEMM once (permuted-K input) -> stats + per-group min/max ----
__global__ __launch_bounds__(256) void l3fused_kernel(
    const unsigned short* __restrict__ y2, const float* __restrict__ W3,
    const float* __restrict__ b3, const float* __restrict__ bn2,
    float* __restrict__ mnbuf, float* __restrict__ mxbuf,   // [b][ch][s] f32
    float* __restrict__ partials) {
  constexpr int NT = 8;
  const int lane = threadIdx.x & 63, wv = threadIdx.x >> 6;
  const int quad = lane >> 4, l16 = lane & 15;
  s16x8 bfrag[NT][2];
  float biasr[NT];
#pragma unroll
  for (int t = 0; t < NT; t++) {
    int n = l16 + 16 * t;
    biasr[t] = b3[n];
#pragma unroll
    for (int kc = 0; kc < 2; kc++)
#pragma unroll
      for (int j = 0; j < 8; j++)
        bfrag[t][kc][j] = rne_bf16(W3[(size_t)n * 64 + permc(kc * 32 + quad * 8 + j)]);
  }
  v2f sc2[2][4], sh2[2][4];
#pragma unroll
  for (int kc = 0; kc < 2; kc++)
#pragma unroll
    for (int p = 0; p < 4; p++) {
      int c0 = permc(kc * 32 + quad * 8 + 2 * p);
      int c1 = permc(kc * 32 + quad * 8 + 2 * p + 1);
      sc2[kc][p] = (v2f){bn2[c0], bn2[c1]};
      sh2[kc][p] = (v2f){bn2[64 + c0], bn2[64 + c1]};
    }
  float s0[NT], s1[NT];
#pragma unroll
  for (int t = 0; t < NT; t++) { s0[t] = 0.f; s1[t] = 0.f; }
  __shared__ float tmx[128 * 4], tmn[128 * 4];
  for (int g0 = blockIdx.x; g0 < 4096; g0 += 1024) {
    const int gq = g0 * 4 + wv;
    float mx[NT], mn[NT];
#pragma unroll
    for (int t = 0; t < NT; t++) { mx[t] = -1e30f; mn[t] = 1e30f; }
#pragma unroll
    for (int mt2 = 0; mt2 < 2; mt2++) {
      int row = gq * 32 + mt2 * 16 + l16;
      const u32* p = (const u32*)(y2 + (size_t)row * 64 + quad * 8);
      s16x8 a0, a1;
      u32* a0u = (u32*)&a0; u32* a1u = (u32*)&a1;
#pragma unroll
      for (int q = 0; q < 4; q++) {
        a0u[q] = bnrelu_pack(p[q], sc2[0][q], sh2[0][q]);
        a1u[q] = bnrelu_pack(p[16 + q], sc2[1][q], sh2[1][q]);
      }
#pragma unroll
      for (int t = 0; t < NT; t++) {
        f32x4 acc = (f32x4){biasr[t], biasr[t], biasr[t], biasr[t]};
        acc = mfma16(a0, bfrag[t][0], acc);
        acc = mfma16(a1, bfrag[t][1], acc);
#pragma unroll
        for (int r = 0; r < 4; r++) {
          float v = acc[r];
          s0[t] += v; s1[t] = fmaf(v, v, s1[t]);
          mx[t] = fmaxf(mx[t], v); mn[t] = fminf(mn[t], v);
        }
      }
    }
#pragma unroll
    for (int t = 0; t < NT; t++) {
      mx[t] = fmaxf(mx[t], __shfl_xor(mx[t], 16));
      mx[t] = fmaxf(mx[t], __shfl_xor(mx[t], 32));
      mn[t] = fminf(mn[t], __shfl_xor(mn[t], 16));
      mn[t] = fminf(mn[t], __shfl_xor(mn[t], 32));
    }
    if (quad == 0) {
#pragma unroll
      for (int t = 0; t < NT; t++) {
        tmx[(l16 + 16 * t) * 4 + wv] = mx[t];
        tmn[(l16 + 16 * t) * 4 + wv] = mn[t];
      }
    }
    __syncthreads();
    if (threadIdx.x < 128) {
      int b = g0 >> 8;
      int s0i = (g0 & 255) * 4;
      size_t o = ((size_t)b * 128 + threadIdx.x) * 1024 + s0i;
      *(float4*)&mxbuf[o] = *(float4*)&tmx[threadIdx.x * 4];
      *(float4*)&mnbuf[o] = *(float4*)&tmn[threadIdx.x * 4];
    }
    __syncthreads();
  }
#pragma unroll
  for (int t = 0; t < NT; t++) {
    s0[t] += __shfl_xor(s0[t], 16); s0[t] += __shfl_xor(s0[t], 32);
    s1[t] += __shfl_xor(s1[t], 16); s1[t] += __shfl_xor(s1[t], 32);
  }
  __shared__ float sp[4 * 2 * 128];
  if (quad == 0) {
#pragma unroll
    for (int t = 0; t < NT; t++) {
      sp[wv * 256 + l16 + 16 * t] = s0[t];
      sp[wv * 256 + 128 + l16 + 16 * t] = s1[t];
    }
  }
  __syncthreads();
  {
    int tt = threadIdx.x;
    float p = sp[tt] + sp[256 + tt] + sp[512 + tt] + sp[768 + tt];
    partials[(size_t)tt * PNB + blockIdx.x] = p;
  }
}

// ---------------- fused finalize3 + apply: each block covers exactly ONE channel ------------
__global__ __launch_bounds__(256) void l3final_kernel(
    const float* __restrict__ partials, const float* __restrict__ g,
    const float* __restrict__ be, const float* __restrict__ mnbuf,
    const float* __restrict__ mxbuf, float* __restrict__ out1) {
  const int t = threadIdx.x;
  const int ch = (blockIdx.x >> 2) & 127;
  const int lane = t & 63, wv = t >> 6;
  float s0 = 0.f, s1 = 0.f;
  for (int bb = t; bb < PNB; bb += 256) {
    s0 += partials[(size_t)ch * PNB + bb];
    s1 += partials[(size_t)(128 + ch) * PNB + bb];
  }
#pragma unroll
  for (int off = 32; off; off >>= 1) {
    s0 += __shfl_xor(s0, off);
    s1 += __shfl_xor(s1, off);
  }
  __shared__ float r0[4], r1[4];
  __shared__ float bnsh[2];
  if (lane == 0) { r0[wv] = s0; r1[wv] = s1; }
  __syncthreads();
  if (t == 0) {
    double d0 = (double)r0[0] + r0[1] + r0[2] + r0[3];
    double d1 = (double)r1[0] + r1[1] + r1[2] + r1[3];
    double N = (double)ROWS;
    double mean = d0 / N;
    double var = d1 / N - mean * mean;
    double scale = (double)g[ch] / sqrt(var + 1e-5);
    bnsh[0] = (float)scale;
    bnsh[1] = (float)((double)be[ch] - mean * scale);
  }
  __syncthreads();
  float s = bnsh[0], h = bnsh[1];
  int i = blockIdx.x * 256 + t;
  float v = (s > 0.f) ? mxbuf[i] : mnbuf[i];
  out1[i] = fmaxf(fmaf(v, s, h), 0.f);
}

extern "C" void kernel_launch(void* const* d_in, const int* in_sizes, int n_in,
                              void* d_out, int out_size, void* d_ws, size_t ws_size,
                              hipStream_t stream) {
  const float* xyz = (const float*)d_in[0];
  const float* pts = (const float*)d_in[1];
  const float* W1 = (const float*)d_in[2],  *b1 = (const float*)d_in[3];
  const float* g1 = (const float*)d_in[4],  *be1 = (const float*)d_in[5];
  const float* W2 = (const float*)d_in[6],  *b2 = (const float*)d_in[7];
  const float* g2 = (const float*)d_in[8],  *be2 = (const float*)d_in[9];
  const float* W3 = (const float*)d_in[10], *b3 = (const float*)d_in[11];
  const float* g3 = (const float*)d_in[12], *be3 = (const float*)d_in[13];
  float* out0 = (float*)d_out;                 // xyz_query_pc [16,3,1024]
  float* out1 = out0 + B_ * 3 * S_;            // new_points   [16,128,1024]

  char* ws = (char*)d_ws;
  float* new_xyz  = (float*)(ws);
  float* bn1      = (float*)(ws + 196608);
  float* bn2      = bn1 + 128;
  int*   gidx     = (int*)(ws + 198656);
  float* partials = (float*)(ws + 2295808);
  unsigned short* y1 = (unsigned short*)(ws + 4392960);            // 64 MB bf16
  unsigned short* y2 = (unsigned short*)(ws + 4392960 + 67108864); // 64 MB bf16 (K-permuted)
  float* mnbuf = (float*)(ws + 4392960);                           // reuse y1 space
  float* mxbuf = (float*)(ws + 4392960 + 8388608);

  fps_kernel<<<B_, 1024, 0, stream>>>(xyz, out0, new_xyz);
  ballq_kernel<<<4096, 256, 0, stream>>>(xyz, new_xyz, gidx);
  layer1_kernel<<<PNB, 256, 0, stream>>>(xyz, pts, new_xyz, gidx, W1, b1, y1, partials);
  finalize_kernel<<<64, 256, 0, stream>>>(partials, 64, g1, be1, bn1);
  layer2_kernel<<<PNB, 256, 0, stream>>>(y1, W2, b2, bn1, y2, partials);
  finalize_kernel<<<64, 256, 0, stream>>>(partials, 64, g2, be2, bn2);
  l3fused_kernel<<<PNB, 256, 0, stream>>>(y2, W3, b3, bn2, mnbuf, mxbuf, partials);
  l3final_kernel<<<8192, 256, 0, stream>>>(partials, g3, be3, mnbuf, mxbuf, out1);
}

// Round 13
// 874.577 us; speedup vs baseline: 1.2161x; 1.2161x over previous
//
#include <hip/hip_runtime.h>

#pragma clang fp contract(off)

#define NPT 4096
#define B_ 16
#define S_ 1024
#define K_ 32
#define ROWS (B_*S_*K_)   // 524288
#define PNB 1024          // partial-stats blocks (layer kernels' grid)

typedef float v2f __attribute__((ext_vector_type(2)));
typedef unsigned int u32;
typedef unsigned long long u64;
typedef __attribute__((ext_vector_type(8))) short s16x8;
typedef __attribute__((ext_vector_type(4))) float f32x4;

__device__ __forceinline__ float rlf(float v, int l) {
  return __uint_as_float(__builtin_amdgcn_readlane(__float_as_uint(v), l));
}

__device__ __forceinline__ short rne_bf16(float x) {
  u32 b = __float_as_uint(x);
  b += 0x7FFFu + ((b >> 16) & 1u);
  return (short)(b >> 16);
}
__device__ __forceinline__ u32 rne_bits(float x) {   // rounded bits, result in high 16
  u32 b = __float_as_uint(x);
  return b + 0x7FFFu + ((b >> 16) & 1u);
}

__device__ __forceinline__ f32x4 mfma16(s16x8 a, s16x8 b, f32x4 c) {
  return __builtin_amdgcn_mfma_f32_16x16x32_bf16(a, b, c, 0, 0, 0);
}

// stored-position -> original channel permutation for y2 (layer2 fast stores)
__device__ __forceinline__ int permc(int p) { return ((p & 3) << 4) | (p >> 2); }

// BN+relu+RNE-pack for a bf16 pair held in one dword. Bit-exact vs scalar path.
__device__ __forceinline__ u32 bnrelu_pack(u32 d, v2f sc, v2f sh) {
  v2f a;
  a.x = __uint_as_float(d << 16);
  a.y = __uint_as_float(d & 0xFFFF0000u);
  v2f z = __builtin_elementwise_fma(a, sc, sh);
  z = __builtin_elementwise_max(z, (v2f){0.f, 0.f});
  u32 zx = rne_bits(z.x), zy = rne_bits(z.y);
  return __builtin_amdgcn_perm(zy, zx, 0x07060302);   // {zx.hi16, zy.hi16}
}

template <int CTRL>
__device__ __forceinline__ u64 dpp_u64(u64 x) {
  int lo = (int)(u32)x, hi = (int)(u32)(x >> 32);
  lo = __builtin_amdgcn_update_dpp(lo, lo, CTRL, 0xF, 0xF, false);
  hi = __builtin_amdgcn_update_dpp(hi, hi, CTRL, 0xF, 0xF, false);
  return ((u64)(u32)hi << 32) | (u32)lo;
}
// full-wave f64 max -> lane 63. Keys are positive doubles => f64 order == u64 order.
__device__ __forceinline__ double wave_max_f64(double k) {
  k = fmax(k, __longlong_as_double((long long)dpp_u64<0x111>((u64)__double_as_longlong(k))));
  k = fmax(k, __longlong_as_double((long long)dpp_u64<0x112>((u64)__double_as_longlong(k))));
  k = fmax(k, __longlong_as_double((long long)dpp_u64<0x114>((u64)__double_as_longlong(k))));
  k = fmax(k, __longlong_as_double((long long)dpp_u64<0x118>((u64)__double_as_longlong(k))));
  k = fmax(k, __longlong_as_double((long long)dpp_u64<0x142>((u64)__double_as_longlong(k))));
  k = fmax(k, __longlong_as_double((long long)dpp_u64<0x143>((u64)__double_as_longlong(k))));
  return k;
}

__device__ __forceinline__ double mkkey(float d, u32 lo) {
  return __longlong_as_double((long long)(((u64)__float_as_uint(d) << 32) | lo));
}

// ---------------- FPS: one block per batch, 512 threads, 8 pts/thread ----------------
// FINAL structure (R5/R8, 588 us = 1024 iter x ~1378 cyc). Wave-count curve measured:
// 1 wave/SIMD=1914 cyc/iter (R6), 2=1378 (R5), 4=1823 (R12). Issue-cutting restructures
// (R7 value+resolve, R10 2-barrier global-resolve) both lengthened the serial chain.
// DO NOT retune.
__global__ __launch_bounds__(512) void fps_kernel(const float* __restrict__ xyz,
    float* __restrict__ out0, float* __restrict__ new_xyz) {
  const int b = blockIdx.x, t = threadIdx.x;
  const int lane = t & 63;
  const float* xb = xyz + (size_t)b * 3 * NPT;
  __shared__ float4 spt[NPT];       // 64 KB: (x,y,z,-)
  __shared__ u64 skey[3];           // 3-slot rotating argmax cell
  __shared__ int sfar[S_];          // selected index per iteration
  // coalesced stage into LDS
#pragma unroll
  for (int j = 0; j < 8; j++) {
    int m = t + j * 512;
    spt[m] = make_float4(xb[m], xb[NPT + m], xb[2 * NPT + m], 0.f);
  }
  if (t < 3) skey[t] = 0ull;
  // lane-local consecutive points n = t*8+i, loaded from global (coalesced float4)
  const float4* xb4 = (const float4*)xb;
  float4 X0 = xb4[t * 2], X1 = xb4[t * 2 + 1];
  float4 Y0 = xb4[NPT / 4 + t * 2], Y1 = xb4[NPT / 4 + t * 2 + 1];
  float4 Z0 = xb4[2 * NPT / 4 + t * 2], Z1 = xb4[2 * NPT / 4 + t * 2 + 1];
  v2f px[4], py[4], pz[4], ds[4];
  px[0] = (v2f){X0.x, X0.y}; px[1] = (v2f){X0.z, X0.w}; px[2] = (v2f){X1.x, X1.y}; px[3] = (v2f){X1.z, X1.w};
  py[0] = (v2f){Y0.x, Y0.y}; py[1] = (v2f){Y0.z, Y0.w}; py[2] = (v2f){Y1.x, Y1.y}; py[3] = (v2f){Y1.z, Y1.w};
  pz[0] = (v2f){Z0.x, Z0.y}; pz[1] = (v2f){Z0.z, Z0.w}; pz[2] = (v2f){Z1.x, Z1.y}; pz[3] = (v2f){Z1.z, Z1.w};
  const int base = t * 8;
  u32 lo[8];
#pragma unroll
  for (int i = 0; i < 8; i++) lo[i] = ~(u32)(base + i);
#pragma unroll
  for (int j = 0; j < 4; j++) ds[j] = (v2f){1e10f, 1e10f};
  __syncthreads();
  int far = 0, slot = 0;
  for (int it = 0; it < S_; ++it) {
    if (t == 0) sfar[it] = far;
    float4 c = spt[far];
    v2f cx = (v2f){c.x, c.x}, cy = (v2f){c.y, c.y}, cz = (v2f){c.z, c.z};
#pragma unroll
    for (int j = 0; j < 4; j++) {
      // exact ref op order per element: ((dx*dx + dy*dy) + dz*dz), contraction OFF
      v2f dx = px[j] - cx, dy = py[j] - cy, dz = pz[j] - cz;
      v2f s = dx * dx + dy * dy;
      v2f d = s + dz * dz;
      v2f nd;
      nd.x = fminf(ds[j].x, d.x);
      nd.y = fminf(ds[j].y, d.y);
      ds[j] = nd;
    }
    // f64 sortable keys: max dist, tie -> min index (via ~idx in low word)
    double k = fmax(fmax(fmax(mkkey(ds[0].x, lo[0]), mkkey(ds[0].y, lo[1])),
                         fmax(mkkey(ds[1].x, lo[2]), mkkey(ds[1].y, lo[3]))),
                    fmax(fmax(mkkey(ds[2].x, lo[4]), mkkey(ds[2].y, lo[5])),
                         fmax(mkkey(ds[3].x, lo[6]), mkkey(ds[3].y, lo[7]))));
    k = wave_max_f64(k);
    if (lane == 63) atomicMax(&skey[slot], (u64)__double_as_longlong(k));
    __syncthreads();
    u64 kk = skey[slot];
    if (t == 0) skey[slot == 0 ? 2 : slot - 1] = 0ull;  // reset slot (it+2)%3: safe post-barrier
    far = (int)(~(u32)kk);
    slot = (slot == 2) ? 0 : slot + 1;
  }
  __syncthreads();
  // coalesced writeback of centroids
#pragma unroll
  for (int j = 0; j < 2; j++) {
    int it = t + j * 512;
    float4 p = spt[sfar[it]];
    out0[(b * 3 + 0) * S_ + it] = p.x;
    out0[(b * 3 + 1) * S_ + it] = p.y;
    out0[(b * 3 + 2) * S_ + it] = p.z;
    float* nz = new_xyz + ((size_t)b * S_ + it) * 3;
    nz[0] = p.x; nz[1] = p.y; nz[2] = p.z;
  }
}

// ---------------- Ball query: one wave per query ----------------
__global__ __launch_bounds__(256) void ballq_kernel(const float* __restrict__ xyz,
    const float* __restrict__ new_xyz, int* __restrict__ gidx) {
  const int wid = (blockIdx.x * 256 + threadIdx.x) >> 6;   // 16384 queries
  const int lane = threadIdx.x & 63;
  const int b = wid >> 10;
  const float* xb = xyz + (size_t)b * 3 * NPT;
  const float qx = new_xyz[(size_t)wid * 3 + 0];
  const float qy = new_xyz[(size_t)wid * 3 + 1];
  const float qz = new_xyz[(size_t)wid * 3 + 2];
  const float R2 = (float)(0.4 * 0.4);
  int* g = gidx + (size_t)wid * K_;
  int cnt = 0, firstIdx = 0x7fffffff;
  for (int c0 = 0; c0 < NPT && cnt < K_; c0 += 64) {
    int n = c0 + lane;
    float dx = __fadd_rn(qx, -xb[n]);
    float dy = __fadd_rn(qy, -xb[NPT + n]);
    float dz = __fadd_rn(qz, -xb[2 * NPT + n]);
    float sq = __fadd_rn(__fadd_rn(__fmul_rn(dx, dx), __fmul_rn(dy, dy)), __fmul_rn(dz, dz));
    bool inr = !(sq > R2);
    unsigned long long m = __ballot(inr);
    if (inr) {
      int pos = cnt + (int)__popcll(m & ((1ull << lane) - 1ull));
      if (pos < K_) g[pos] = n;
    }
    if (firstIdx == 0x7fffffff && m) firstIdx = c0 + (int)__builtin_ctzll(m);
    cnt += (int)__popcll(m);
  }
  if (lane >= cnt && lane < K_) g[lane] = firstIdx;
}

// ---------------- Layer 1: gather+concat, 6->64, 4 rows/wave-iter, bf16 out + stats --------
__global__ __launch_bounds__(256) void layer1_kernel(
    const float* __restrict__ xyz, const float* __restrict__ pts,
    const float* __restrict__ new_xyz, const int* __restrict__ gidx,
    const float* __restrict__ W1, const float* __restrict__ b1,
    unsigned short* __restrict__ y1, float* __restrict__ partials) {
  __shared__ float sp[4 * 2 * 64];
  const int lane = threadIdx.x & 63, wv = threadIdx.x >> 6;
  const int nw = gridDim.x * 4;
  float w[6];
#pragma unroll
  for (int c = 0; c < 6; c++) w[c] = W1[lane * 6 + c];
  const float bias = b1[lane];
  float s0 = 0.f, s1 = 0.f;
  const int grp = lane >> 3;          // 0..7; groups 0..3 gather for rows A..D
  const int gc = lane & 7;            // channel slot within group (0..5 used)
  for (int r = (blockIdx.x * 4 + wv) * 4; r < ROWS; r += nw * 4) {
    float v = 0.f;
    if (grp < 4 && gc < 6) {
      int rr = r + grp;
      int gi = gidx[rr];
      int bs = rr >> 5, bb = bs >> 10;
      if (gc < 3) v = xyz[((size_t)bb * 3 + gc) * NPT + gi] - new_xyz[(size_t)bs * 3 + gc];
      else        v = pts[((size_t)bb * 3 + (gc - 3)) * NPT + gi];
    }
    float acc[4];
#pragma unroll
    for (int q = 0; q < 4; q++) acc[q] = bias;
#pragma unroll
    for (int c = 0; c < 6; c++) {
#pragma unroll
      for (int q = 0; q < 4; q++) acc[q] = fmaf(rlf(v, q * 8 + c), w[c], acc[q]);
    }
#pragma unroll
    for (int q = 0; q < 4; q++) {
      y1[(size_t)(r + q) * 64 + lane] = (unsigned short)rne_bf16(acc[q]);
      s0 += acc[q]; s1 = fmaf(acc[q], acc[q], s1);
    }
  }
  sp[(wv * 2 + 0) * 64 + lane] = s0;
  sp[(wv * 2 + 1) * 64 + lane] = s1;
  __syncthreads();
  if (threadIdx.x < 128) {
    float p = sp[threadIdx.x] + sp[threadIdx.x + 128] + sp[threadIdx.x + 256] + sp[threadIdx.x + 384];
    partials[(size_t)threadIdx.x * PNB + blockIdx.x] = p;
  }
}

// ---------------- Layer 2 (MFMA): bn1+relu (pk) -> GEMM 64->64, 2 M-tiles/iter; permuted-K ----
__global__ __launch_bounds__(256) void layer2_kernel(
    const unsigned short* __restrict__ y1, const float* __restrict__ W,
    const float* __restrict__ bias, const float* __restrict__ bnin,
    unsigned short* __restrict__ y2, float* __restrict__ partials) {
  constexpr int NT = 4;
  const int lane = threadIdx.x & 63, wv = threadIdx.x >> 6;
  const int quad = lane >> 4, l16 = lane & 15;
  s16x8 bfrag[NT][2];
  float biasr[NT];
#pragma unroll
  for (int t = 0; t < NT; t++) {
    int n = l16 + 16 * t;
    biasr[t] = bias[n];
#pragma unroll
    for (int kc = 0; kc < 2; kc++)
#pragma unroll
      for (int j = 0; j < 8; j++)
        bfrag[t][kc][j] = rne_bf16(W[(size_t)n * 64 + kc * 32 + quad * 8 + j]);
  }
  v2f sc2[2][4], sh2[2][4];
#pragma unroll
  for (int kc = 0; kc < 2; kc++)
#pragma unroll
    for (int p = 0; p < 4; p++) {
      int k0 = kc * 32 + quad * 8 + 2 * p;
      sc2[kc][p] = (v2f){bnin[k0], bnin[k0 + 1]};
      sh2[kc][p] = (v2f){bnin[64 + k0], bnin[64 + k0 + 1]};
    }
  float s0[NT], s1[NT];
#pragma unroll
  for (int t = 0; t < NT; t++) { s0[t] = 0.f; s1[t] = 0.f; }
  const int nwaves = gridDim.x * 4;
  for (int mt = (blockIdx.x * 4 + wv) * 2; mt < ROWS / 16; mt += nwaves * 2) {
    const u32* p0 = (const u32*)(y1 + (size_t)(mt * 16 + l16) * 64 + quad * 8);
    const u32* p1 = (const u32*)(y1 + (size_t)((mt + 1) * 16 + l16) * 64 + quad * 8);
    u32 d[2][8];
#pragma unroll
    for (int q = 0; q < 4; q++) { d[0][q] = p0[q]; d[0][4 + q] = p0[16 + q]; }
#pragma unroll
    for (int q = 0; q < 4; q++) { d[1][q] = p1[q]; d[1][4 + q] = p1[16 + q]; }
    s16x8 a[2][2];
#pragma unroll
    for (int m2 = 0; m2 < 2; m2++) {
      u32* a0u = (u32*)&a[m2][0]; u32* a1u = (u32*)&a[m2][1];
#pragma unroll
      for (int q = 0; q < 4; q++) {
        a0u[q] = bnrelu_pack(d[m2][q], sc2[0][q], sh2[0][q]);
        a1u[q] = bnrelu_pack(d[m2][4 + q], sc2[1][q], sh2[1][q]);
      }
    }
    f32x4 acc[2][NT];
#pragma unroll
    for (int m2 = 0; m2 < 2; m2++)
#pragma unroll
      for (int t = 0; t < NT; t++) {
        acc[m2][t] = (f32x4){biasr[t], biasr[t], biasr[t], biasr[t]};
        acc[m2][t] = mfma16(a[m2][0], bfrag[t][0], acc[m2][t]);
        acc[m2][t] = mfma16(a[m2][1], bfrag[t][1], acc[m2][t]);
      }
#pragma unroll
    for (int m2 = 0; m2 < 2; m2++) {
#pragma unroll
      for (int r = 0; r < 4; r++) {
        u32 b01 = __builtin_amdgcn_perm(rne_bits(acc[m2][1][r]), rne_bits(acc[m2][0][r]), 0x07060302);
        u32 b23 = __builtin_amdgcn_perm(rne_bits(acc[m2][3][r]), rne_bits(acc[m2][2][r]), 0x07060302);
        int m = (mt + m2) * 16 + quad * 4 + r;
        *(uint2*)(y2 + (size_t)m * 64 + 4 * l16) = make_uint2(b01, b23);
      }
#pragma unroll
      for (int t = 0; t < NT; t++)
#pragma unroll
        for (int r = 0; r < 4; r++) {
          float v = acc[m2][t][r];
          s0[t] += v; s1[t] = fmaf(v, v, s1[t]);
        }
    }
  }
#pragma unroll
  for (int t = 0; t < NT; t++) {
    s0[t] += __shfl_xor(s0[t], 16); s0[t] += __shfl_xor(s0[t], 32);
    s1[t] += __shfl_xor(s1[t], 16); s1[t] += __shfl_xor(s1[t], 32);
  }
  __shared__ float sp[4 * 2 * 64];
  if (quad == 0) {
#pragma unroll
    for (int t = 0; t < NT; t++) {
      sp[wv * 128 + l16 + 16 * t] = s0[t];
      sp[wv * 128 + 64 + l16 + 16 * t] = s1[t];
    }
  }
  __syncthreads();
  if (threadIdx.x < 128) {
    int tt = threadIdx.x;
    float p = sp[tt] + sp[128 + tt] + sp[256 + tt] + sp[384 + tt];
    partials[(size_t)tt * PNB + blockIdx.x] = p;
  }
}

// ---------------- fold partials -> bn scale/shift ----------------
__global__ __launch_bounds__(256) void finalize_kernel(const float* __restrict__ partials,
    int cout, const float* __restrict__ g, const float* __restrict__ be,
    float* __restrict__ bn) {
  const int c = blockIdx.x;
  const int t = threadIdx.x;
  const int lane = t & 63, wv = t >> 6;
  float s0 = 0.f, s1 = 0.f;
  for (int bb = t; bb < PNB; bb += 256) {
    s0 += partials[(size_t)c * PNB + bb];
    s1 += partials[(size_t)(cout + c) * PNB + bb];
  }
#pragma unroll
  for (int off = 32; off; off >>= 1) {
    s0 += __shfl_xor(s0, off);
    s1 += __shfl_xor(s1, off);
  }
  __shared__ float r0[4], r1[4];
  if (lane == 0) { r0[wv] = s0; r1[wv] = s1; }
  __syncthreads();
  if (t == 0) {
    double d0 = (double)r0[0] + r0[1] + r0[2] + r0[3];
    double d1 = (double)r1[0] + r1[1] + r1[2] + r1[3];
    double N = (double)ROWS;
    double mean = d0 / N;
    double var = d1 / N - mean * mean;
    double scale = (double)g[c] / sqrt(var + 1e-5);
    bn[c] = (float)scale;
    bn[cout + c] = (float)((double)be[c] - mean * scale);
  }
}

// ---------------- Fused layer3: GEMM once (permuted-K input) -> stats + per-group min/max ----
__global__ __launch_bounds__(256) void l3fused_kernel(
    const unsigned short* __restrict__ y2, const float* __restrict__ W3,
    const float* __restrict__ b3, const float* __restrict__ bn2,
    float* __restrict__ mnbuf, float* __restrict__ mxbuf,   // [b][ch][s] f32
    float* __restrict__ partials) {
  constexpr int NT = 8;
  const int lane = threadIdx.x & 63, wv = threadIdx.x >> 6;
  const int quad = lane >> 4, l16 = lane & 15;
  s16x8 bfrag[NT][2];
  float biasr[NT];
#pragma unroll
  for (int t = 0; t < NT; t++) {
    int n = l16 + 16 * t;
    biasr[t] = b3[n];
#pragma unroll
    for (int kc = 0; kc < 2; kc++)
#pragma unroll
      for (int j = 0; j < 8; j++)
        bfrag[t][kc][j] = rne_bf16(W3[(size_t)n * 64 + permc(kc * 32 + quad * 8 + j)]);
  }
  v2f sc2[2][4], sh2[2][4];
#pragma unroll
  for (int kc = 0; kc < 2; kc++)
#pragma unroll
    for (int p = 0; p < 4; p++) {
      int c0 = permc(kc * 32 + quad * 8 + 2 * p);
      int c1 = permc(kc * 32 + quad * 8 + 2 * p + 1);
      sc2[kc][p] = (v2f){bn2[c0], bn2[c1]};
      sh2[kc][p] = (v2f){bn2[64 + c0], bn2[64 + c1]};
    }
  float s0[NT], s1[NT];
#pragma unroll
  for (int t = 0; t < NT; t++) { s0[t] = 0.f; s1[t] = 0.f; }
  __shared__ float tmx[128 * 4], tmn[128 * 4];
  for (int g0 = blockIdx.x; g0 < 4096; g0 += 1024) {
    const int gq = g0 * 4 + wv;
    float mx[NT], mn[NT];
#pragma unroll
    for (int t = 0; t < NT; t++) { mx[t] = -1e30f; mn[t] = 1e30f; }
#pragma unroll
    for (int mt2 = 0; mt2 < 2; mt2++) {
      int row = gq * 32 + mt2 * 16 + l16;
      const u32* p = (const u32*)(y2 + (size_t)row * 64 + quad * 8);
      s16x8 a0, a1;
      u32* a0u = (u32*)&a0; u32* a1u = (u32*)&a1;
#pragma unroll
      for (int q = 0; q < 4; q++) {
        a0u[q] = bnrelu_pack(p[q], sc2[0][q], sh2[0][q]);
        a1u[q] = bnrelu_pack(p[16 + q], sc2[1][q], sh2[1][q]);
      }
#pragma unroll
      for (int t = 0; t < NT; t++) {
        f32x4 acc = (f32x4){biasr[t], biasr[t], biasr[t], biasr[t]};
        acc = mfma16(a0, bfrag[t][0], acc);
        acc = mfma16(a1, bfrag[t][1], acc);
#pragma unroll
        for (int r = 0; r < 4; r++) {
          float v = acc[r];
          s0[t] += v; s1[t] = fmaf(v, v, s1[t]);
          mx[t] = fmaxf(mx[t], v); mn[t] = fminf(mn[t], v);
        }
      }
    }
#pragma unroll
    for (int t = 0; t < NT; t++) {
      mx[t] = fmaxf(mx[t], __shfl_xor(mx[t], 16));
      mx[t] = fmaxf(mx[t], __shfl_xor(mx[t], 32));
      mn[t] = fminf(mn[t], __shfl_xor(mn[t], 16));
      mn[t] = fminf(mn[t], __shfl_xor(mn[t], 32));
    }
    if (quad == 0) {
#pragma unroll
      for (int t = 0; t < NT; t++) {
        tmx[(l16 + 16 * t) * 4 + wv] = mx[t];
        tmn[(l16 + 16 * t) * 4 + wv] = mn[t];
      }
    }
    __syncthreads();
    if (threadIdx.x < 128) {
      int b = g0 >> 8;
      int s0i = (g0 & 255) * 4;
      size_t o = ((size_t)b * 128 + threadIdx.x) * 1024 + s0i;
      *(float4*)&mxbuf[o] = *(float4*)&tmx[threadIdx.x * 4];
      *(float4*)&mnbuf[o] = *(float4*)&tmn[threadIdx.x * 4];
    }
    __syncthreads();
  }
#pragma unroll
  for (int t = 0; t < NT; t++) {
    s0[t] += __shfl_xor(s0[t], 16); s0[t] += __shfl_xor(s0[t], 32);
    s1[t] += __shfl_xor(s1[t], 16); s1[t] += __shfl_xor(s1[t], 32);
  }
  __shared__ float sp[4 * 2 * 128];
  if (quad == 0) {
#pragma unroll
    for (int t = 0; t < NT; t++) {
      sp[wv * 256 + l16 + 16 * t] = s0[t];
      sp[wv * 256 + 128 + l16 + 16 * t] = s1[t];
    }
  }
  __syncthreads();
  {
    int tt = threadIdx.x;
    float p = sp[tt] + sp[256 + tt] + sp[512 + tt] + sp[768 + tt];
    partials[(size_t)tt * PNB + blockIdx.x] = p;
  }
}

// ---------------- fused finalize3 + apply: each block covers exactly ONE channel ------------
__global__ __launch_bounds__(256) void l3final_kernel(
    const float* __restrict__ partials, const float* __restrict__ g,
    const float* __restrict__ be, const float* __restrict__ mnbuf,
    const float* __restrict__ mxbuf, float* __restrict__ out1) {
  const int t = threadIdx.x;
  const int ch = (blockIdx.x >> 2) & 127;
  const int lane = t & 63, wv = t >> 6;
  float s0 = 0.f, s1 = 0.f;
  for (int bb = t; bb < PNB; bb += 256) {
    s0 += partials[(size_t)ch * PNB + bb];
    s1 += partials[(size_t)(128 + ch) * PNB + bb];
  }
#pragma unroll
  for (int off = 32; off; off >>= 1) {
    s0 += __shfl_xor(s0, off);
    s1 += __shfl_xor(s1, off);
  }
  __shared__ float r0[4], r1[4];
  __shared__ float bnsh[2];
  if (lane == 0) { r0[wv] = s0; r1[wv] = s1; }
  __syncthreads();
  if (t == 0) {
    double d0 = (double)r0[0] + r0[1] + r0[2] + r0[3];
    double d1 = (double)r1[0] + r1[1] + r1[2] + r1[3];
    double N = (double)ROWS;
    double mean = d0 / N;
    double var = d1 / N - mean * mean;
    double scale = (double)g[ch] / sqrt(var + 1e-5);
    bnsh[0] = (float)scale;
    bnsh[1] = (float)((double)be[ch] - mean * scale);
  }
  __syncthreads();
  float s = bnsh[0], h = bnsh[1];
  int i = blockIdx.x * 256 + t;
  float v = (s > 0.f) ? mxbuf[i] : mnbuf[i];
  out1[i] = fmaxf(fmaf(v, s, h), 0.f);
}

extern "C" void kernel_launch(void* const* d_in, const int* in_sizes, int n_in,
                              void* d_out, int out_size, void* d_ws, size_t ws_size,
                              hipStream_t stream) {
  const float* xyz = (const float*)d_in[0];
  const float* pts = (const float*)d_in[1];
  const float* W1 = (const float*)d_in[2],  *b1 = (const float*)d_in[3];
  const float* g1 = (const float*)d_in[4],  *be1 = (const float*)d_in[5];
  const float* W2 = (const float*)d_in[6],  *b2 = (const float*)d_in[7];
  const float* g2 = (const float*)d_in[8],  *be2 = (const float*)d_in[9];
  const float* W3 = (const float*)d_in[10], *b3 = (const float*)d_in[11];
  const float* g3 = (const float*)d_in[12], *be3 = (const float*)d_in[13];
  float* out0 = (float*)d_out;                 // xyz_query_pc [16,3,1024]
  float* out1 = out0 + B_ * 3 * S_;            // new_points   [16,128,1024]

  char* ws = (char*)d_ws;
  float* new_xyz  = (float*)(ws);
  float* bn1      = (float*)(ws + 196608);
  float* bn2      = bn1 + 128;
  int*   gidx     = (int*)(ws + 198656);
  float* partials = (float*)(ws + 2295808);
  unsigned short* y1 = (unsigned short*)(ws + 4392960);            // 64 MB bf16
  unsigned short* y2 = (unsigned short*)(ws + 4392960 + 67108864); // 64 MB bf16 (K-permuted)
  float* mnbuf = (float*)(ws + 4392960);                           // reuse y1 space
  float* mxbuf = (float*)(ws + 4392960 + 8388608);

  fps_kernel<<<B_, 512, 0, stream>>>(xyz, out0, new_xyz);
  ballq_kernel<<<4096, 256, 0, stream>>>(xyz, new_xyz, gidx);
  layer1_kernel<<<PNB, 256, 0, stream>>>(xyz, pts, new_xyz, gidx, W1, b1, y1, partials);
  finalize_kernel<<<64, 256, 0, stream>>>(partials, 64, g1, be1, bn1);
  layer2_kernel<<<PNB, 256, 0, stream>>>(y1, W2, b2, bn1, y2, partials);
  finalize_kernel<<<64, 256, 0, stream>>>(partials, 64, g2, be2, bn2);
  l3fused_kernel<<<PNB, 256, 0, stream>>>(y2, W3, b3, bn2, mnbuf, mxbuf, partials);
  l3final_kernel<<<8192, 256, 0, stream>>>(partials, g3, be3, mnbuf, mxbuf, out1);
}